// Round 4
// baseline (348.544 us; speedup 1.0000x reference)
//
#include <hip/hip_runtime.h>
#include <hip/hip_bf16.h>

typedef short short8 __attribute__((ext_vector_type(8)));
typedef float floatx4 __attribute__((ext_vector_type(4)));
typedef __hip_bfloat16 bf16;

#define GLB(p) ((const __attribute__((address_space(1))) void*)(p))
#define LDSP(p) ((__attribute__((address_space(3))) void*)(p))

__device__ __forceinline__ void gload16(const bf16* g, char* l) {
    __builtin_amdgcn_global_load_lds(GLB(g), LDSP(l), 16, 0, 0);
}

#define VMCNT(n) asm volatile("s_waitcnt vmcnt(" #n ")" ::: "memory")
#define BAR()    __builtin_amdgcn_s_barrier()

// ---- problem sizes ----
// x: (64,128,56,56) f32; out: (64,256,28,28) f32
// xpad:  [64][58][58][128] bf16 (halo=1, conv1 pad baked in)
// actpad:[64][30][30][256] bf16 (halo=1 for conv2 pad)
#define XPAD_BYTES   (64u*58*58*128*2)
#define ACTPAD_BYTES (64u*30*30*256*2)
#define OFF_XPAD   0
#define OFF_ACTPAD (XPAD_BYTES)
#define OFF_W1T    (OFF_ACTPAD + ACTPAD_BYTES)
#define OFF_W2T    (OFF_W1T + 1152u*256*2)
#define OFF_WDST   (OFF_W2T + 2304u*256*2)

// LDS slot layout (64KB/slot, 2 slots): Ah0 [0,16K) Ah1 [16K,32K) Bh0 [32K,48K) Bh1 [48K,64K)
__device__ __constant__ int cOff[4] = {0, 32768, 16384, 49152}; // c0=Ah0 c1=Bh0 c2=Ah1 c3=Bh1

// ---------------- weight transforms: OIHW f32 -> [oc][k] bf16, k=(kh*3+kw)*C+ic
__global__ void wtrans_kernel(const float* __restrict__ w1, const float* __restrict__ w2,
                              const float* __restrict__ wds,
                              bf16* __restrict__ w1t, bf16* __restrict__ w2t,
                              bf16* __restrict__ wdst) {
    int i = blockIdx.x * 256 + threadIdx.x;
    if (i < 256 * 1152) {
        int oc = i / 1152, k = i % 1152, tap = k >> 7, ic = k & 127;
        w1t[i] = __float2bfloat16(w1[(oc * 128 + ic) * 9 + tap]);
    }
    if (i < 256 * 2304) {
        int oc = i / 2304, k = i % 2304, tap = k >> 8, ic = k & 255;
        w2t[i] = __float2bfloat16(w2[(oc * 256 + ic) * 9 + tap]);
    }
    if (i < 256 * 128) {
        wdst[i] = __float2bfloat16(wds[i]); // already [oc][ic]
    }
}

// ---------------- zero ONLY the halos of xpad and actpad
__global__ void halo_zero_kernel(bf16* __restrict__ xpad, bf16* __restrict__ actpad) {
    int i = blockIdx.x * 256 + threadIdx.x;
    uint4 z; z.x = z.y = z.z = z.w = 0;
    const int n0 = 64 * 2 * 58 * 16;
    const int n1 = n0 + 64 * 56 * 2 * 16;
    const int n2 = n1 + 64 * 2 * 30 * 32;
    const int n3 = n2 + 64 * 28 * 2 * 32;
    if (i < n0) {
        int g = i & 15, w = (i >> 4) % 58, q = (i >> 4) / 58;
        int n = q >> 1, h = (q & 1) ? 57 : 0;
        *(uint4*)(xpad + ((size_t)((n * 58 + h) * 58 + w)) * 128 + g * 8) = z;
    } else if (i < n1) {
        int j = i - n0;
        int g = j & 15, q = j >> 4;
        int w = (q & 1) ? 57 : 0, h = (q >> 1) % 56 + 1, n = (q >> 1) / 56;
        *(uint4*)(xpad + ((size_t)((n * 58 + h) * 58 + w)) * 128 + g * 8) = z;
    } else if (i < n2) {
        int j = i - n1;
        int g = j & 31, w = (j >> 5) % 30, q = (j >> 5) / 30;
        int n = q >> 1, h = (q & 1) ? 29 : 0;
        *(uint4*)(actpad + ((size_t)((n * 30 + h) * 30 + w)) * 256 + g * 8) = z;
    } else if (i < n3) {
        int j = i - n2;
        int g = j & 31, q = j >> 5;
        int w = (q & 1) ? 29 : 0, h = (q >> 1) % 28 + 1, n = (q >> 1) / 28;
        *(uint4*)(actpad + ((size_t)((n * 30 + h) * 30 + w)) * 256 + g * 8) = z;
    }
}

// ---------------- x: NCHW f32 -> xpad NHWC bf16 (interior only)
__global__ void xpad_kernel(const float* __restrict__ x, bf16* __restrict__ xpad) {
    int bid = blockIdx.x;
    int n = bid / 56, h = bid % 56;
    __shared__ float tile[128 * 57];
    const float* src = x + ((size_t)n * 128) * 3136 + h * 56;
    for (int e = threadIdx.x; e < 128 * 56; e += 256) {
        int c = e / 56, w = e % 56;
        tile[c * 57 + w] = src[(size_t)c * 3136 + w];
    }
    __syncthreads();
    bf16* dst = xpad + ((size_t)(n * 58 + h + 1) * 58 + 1) * 128;
    for (int e = threadIdx.x; e < 56 * 16; e += 256) {
        int w = e / 16, g = e % 16;
        union { bf16 b[8]; uint4 v; } o;
        #pragma unroll
        for (int j = 0; j < 8; ++j)
            o.b[j] = __float2bfloat16(tile[(g * 8 + j) * 57 + w]);
        *(uint4*)(dst + (size_t)w * 128 + g * 8) = o.v;
    }
}

// =====================================================================
// conv1: 3x3 s2 p1 + b1 + relu -> actpad. 256m x 256oc, BK=64 (18 kt).
// 4-phase m201-style schedule, 2 LDS slots, vmcnt(4) counted.
// =====================================================================
__global__ __launch_bounds__(512, 2) void conv1_kernel(
    const bf16* __restrict__ xpad, const bf16* __restrict__ w1t,
    const float* __restrict__ b1, bf16* __restrict__ actpad)
{
    __shared__ __align__(16) char lds[131072];
    const int t = threadIdx.x;
    const int m0 = blockIdx.x * 256;

    // staging: thread t owns 16B unit (row=t>>2, unit=t&3) of each 16KB chunk half
    const int srow = t >> 2;
    const int su = (t & 3) ^ (srow & 3);          // pre-swizzled source unit
    int xb[2], wb[2];
    #pragma unroll
    for (int r = 0; r < 2; ++r) {
        int m = m0 + r * 128 + srow;
        int n = m / 784, pix = m % 784, oh = pix / 28, ow = pix % 28;
        xb[r] = ((n * 58 + 2 * oh) * 58 + 2 * ow) * 128 + su * 8;
        wb[r] = (r * 128 + srow) * 1152 + su * 8;
    }

    auto STAGE = [&](int kt, int c) {
        char* db_ = lds + ((kt & 1) << 16) + cOff[c] + t * 16;
        int h = c >> 1;
        if ((c & 1) == 0) {  // A chunk
            int tap = kt >> 1;
            int kh = (tap * 11) >> 5, kw = tap - kh * 3;
            int toff = (kh * 58 + kw) * 128 + (kt & 1) * 64 + h * 32;
            gload16(xpad + xb[0] + toff, db_);
            gload16(xpad + xb[1] + toff, db_ + 8192);
        } else {             // B chunk
            int koff = kt * 64 + h * 32;
            gload16(w1t + wb[0] + koff, db_);
            gload16(w1t + wb[1] + koff, db_ + 8192);
        }
    };

    // fragment read offsets (within slot); h adds 16384
    const int lane = t & 63, wid = t >> 6;
    const int wm = (wid >> 2) << 7, woc = (wid & 3) << 6;
    const int lr = lane & 15, kg = lane >> 4;
    const int un = (kg ^ (lr & 3)) << 4;
    int aoff[8], boff[4];
    #pragma unroll
    for (int f = 0; f < 8; ++f) aoff[f] = (wm + f * 16 + lr) * 64 + un;
    #pragma unroll
    for (int g = 0; g < 4; ++g) boff[g] = 32768 + (woc + g * 16 + lr) * 64 + un;

    floatx4 acc[8][4];
    #pragma unroll
    for (int a = 0; a < 8; ++a)
        #pragma unroll
        for (int b = 0; b < 4; ++b) acc[a][b] = (floatx4){0.f, 0.f, 0.f, 0.f};

    STAGE(0, 0); STAGE(0, 1); STAGE(0, 2); STAGE(0, 3);
    VMCNT(4); BAR();

    #pragma unroll 2
    for (int kt = 0; kt < 18; ++kt) {
        const char* base = lds + ((kt & 1) << 16);
        short8 wfr[4], afr[4];
        // ---- ph0: read Bh0 + Ah0[m0..3]; stage c0(kt+1); MFMA m0..3 x h0
        #pragma unroll
        for (int g = 0; g < 4; ++g) wfr[g] = *(const short8*)(base + boff[g]);
        #pragma unroll
        for (int f = 0; f < 4; ++f) afr[f] = *(const short8*)(base + aoff[f]);
        if (kt + 1 < 18) STAGE(kt + 1, 0);
        BAR();
        __builtin_amdgcn_s_setprio(1);
        #pragma unroll
        for (int f = 0; f < 4; ++f)
            #pragma unroll
            for (int g = 0; g < 4; ++g)
                acc[f][g] = __builtin_amdgcn_mfma_f32_16x16x32_bf16(afr[f], wfr[g], acc[f][g], 0, 0, 0);
        __builtin_amdgcn_s_setprio(0);
        BAR();
        // ---- ph1: read Ah0[m4..7]; stage c1(kt+1); MFMA m4..7 x h0; vmcnt
        #pragma unroll
        for (int f = 0; f < 4; ++f) afr[f] = *(const short8*)(base + aoff[4 + f]);
        if (kt + 1 < 18) STAGE(kt + 1, 1);
        BAR();
        __builtin_amdgcn_s_setprio(1);
        #pragma unroll
        for (int f = 0; f < 4; ++f)
            #pragma unroll
            for (int g = 0; g < 4; ++g)
                acc[4 + f][g] = __builtin_amdgcn_mfma_f32_16x16x32_bf16(afr[f], wfr[g], acc[4 + f][g], 0, 0, 0);
        __builtin_amdgcn_s_setprio(0);
        if (kt + 1 < 18) { VMCNT(4); } else { VMCNT(0); }
        BAR();
        // ---- ph2: read Bh1 + Ah1[m0..3]; stage c2(kt+1); MFMA m0..3 x h1
        #pragma unroll
        for (int g = 0; g < 4; ++g) wfr[g] = *(const short8*)(base + 16384 + boff[g]);
        #pragma unroll
        for (int f = 0; f < 4; ++f) afr[f] = *(const short8*)(base + 16384 + aoff[f]);
        if (kt + 1 < 18) STAGE(kt + 1, 2);
        BAR();
        __builtin_amdgcn_s_setprio(1);
        #pragma unroll
        for (int f = 0; f < 4; ++f)
            #pragma unroll
            for (int g = 0; g < 4; ++g)
                acc[f][g] = __builtin_amdgcn_mfma_f32_16x16x32_bf16(afr[f], wfr[g], acc[f][g], 0, 0, 0);
        __builtin_amdgcn_s_setprio(0);
        BAR();
        // ---- ph3: read Ah1[m4..7]; stage c3(kt+1); MFMA m4..7 x h1; vmcnt
        #pragma unroll
        for (int f = 0; f < 4; ++f) afr[f] = *(const short8*)(base + 16384 + aoff[4 + f]);
        if (kt + 1 < 18) STAGE(kt + 1, 3);
        BAR();
        __builtin_amdgcn_s_setprio(1);
        #pragma unroll
        for (int f = 0; f < 4; ++f)
            #pragma unroll
            for (int g = 0; g < 4; ++g)
                acc[4 + f][g] = __builtin_amdgcn_mfma_f32_16x16x32_bf16(afr[f], wfr[g], acc[4 + f][g], 0, 0, 0);
        __builtin_amdgcn_s_setprio(0);
        if (kt + 1 < 18) { VMCNT(4); }
        BAR();
    }

    // epilogue: D rows=m (kg*4+rg), cols=oc (lr)
    #pragma unroll
    for (int fm = 0; fm < 8; ++fm) {
        #pragma unroll
        for (int rg = 0; rg < 4; ++rg) {
            int m = m0 + wm + fm * 16 + (kg << 2) + rg;
            int n = m / 784, pix = m % 784;
            int oh = pix / 28, ow = pix % 28;
            bf16* dst = actpad + ((size_t)(n * 30 + oh + 1) * 30 + (ow + 1)) * 256;
            #pragma unroll
            for (int fo = 0; fo < 4; ++fo) {
                int oc = woc + fo * 16 + lr;
                float v = acc[fm][fo][rg] + b1[oc];
                dst[oc] = __float2bfloat16(fmaxf(v, 0.0f));
            }
        }
    }
}

// =====================================================================
// conv2: 3x3 s1 p1 over actpad + b2 + (1x1 s2 shortcut + bds) + relu -> out.
// 256m x 256oc, K = 2304+128 = 38 kt of 64. Same 4-phase schedule.
// =====================================================================
__global__ __launch_bounds__(512, 2) void conv2_kernel(
    const bf16* __restrict__ actpad, const bf16* __restrict__ xpad,
    const bf16* __restrict__ w2t, const bf16* __restrict__ wdst,
    const float* __restrict__ b2, const float* __restrict__ bds,
    float* __restrict__ out)
{
    __shared__ __align__(16) char lds[131072];
    const int t = threadIdx.x;
    const int m0 = blockIdx.x * 256;

    const int srow = t >> 2;
    const int su = (t & 3) ^ (srow & 3);
    int ab[2], xb[2], wb[2], db2[2];
    #pragma unroll
    for (int r = 0; r < 2; ++r) {
        int m = m0 + r * 128 + srow;
        int n = m / 784, pix = m % 784, oh = pix / 28, ow = pix % 28;
        ab[r]  = ((n * 30 + oh) * 30 + ow) * 256 + su * 8;
        xb[r]  = ((n * 58 + 2 * oh + 1) * 58 + (2 * ow + 1)) * 128 + su * 8;
        wb[r]  = (r * 128 + srow) * 2304 + su * 8;
        db2[r] = (r * 128 + srow) * 128 + su * 8;
    }

    auto STAGE = [&](int kt, int c) {
        char* db_ = lds + ((kt & 1) << 16) + cOff[c] + t * 16;
        int h = c >> 1;
        if ((c & 1) == 0) {  // A chunk
            if (kt < 36) {
                int tap = kt >> 2;
                int kh = (tap * 11) >> 5, kw = tap - kh * 3;
                int toff = (kh * 30 + kw) * 256 + (kt & 3) * 64 + h * 32;
                gload16(actpad + ab[0] + toff, db_);
                gload16(actpad + ab[1] + toff, db_ + 8192);
            } else {
                int toff = (kt - 36) * 64 + h * 32;
                gload16(xpad + xb[0] + toff, db_);
                gload16(xpad + xb[1] + toff, db_ + 8192);
            }
        } else {             // B chunk
            if (kt < 36) {
                int koff = kt * 64 + h * 32;
                gload16(w2t + wb[0] + koff, db_);
                gload16(w2t + wb[1] + koff, db_ + 8192);
            } else {
                int koff = (kt - 36) * 64 + h * 32;
                gload16(wdst + db2[0] + koff, db_);
                gload16(wdst + db2[1] + koff, db_ + 8192);
            }
        }
    };

    const int lane = t & 63, wid = t >> 6;
    const int wm = (wid >> 2) << 7, woc = (wid & 3) << 6;
    const int lr = lane & 15, kg = lane >> 4;
    const int un = (kg ^ (lr & 3)) << 4;
    int aoff[8], boff[4];
    #pragma unroll
    for (int f = 0; f < 8; ++f) aoff[f] = (wm + f * 16 + lr) * 64 + un;
    #pragma unroll
    for (int g = 0; g < 4; ++g) boff[g] = 32768 + (woc + g * 16 + lr) * 64 + un;

    floatx4 acc[8][4];
    #pragma unroll
    for (int a = 0; a < 8; ++a)
        #pragma unroll
        for (int b = 0; b < 4; ++b) acc[a][b] = (floatx4){0.f, 0.f, 0.f, 0.f};

    STAGE(0, 0); STAGE(0, 1); STAGE(0, 2); STAGE(0, 3);
    VMCNT(4); BAR();

    #pragma unroll 2
    for (int kt = 0; kt < 38; ++kt) {
        const char* base = lds + ((kt & 1) << 16);
        short8 wfr[4], afr[4];
        // ---- ph0
        #pragma unroll
        for (int g = 0; g < 4; ++g) wfr[g] = *(const short8*)(base + boff[g]);
        #pragma unroll
        for (int f = 0; f < 4; ++f) afr[f] = *(const short8*)(base + aoff[f]);
        if (kt + 1 < 38) STAGE(kt + 1, 0);
        BAR();
        __builtin_amdgcn_s_setprio(1);
        #pragma unroll
        for (int f = 0; f < 4; ++f)
            #pragma unroll
            for (int g = 0; g < 4; ++g)
                acc[f][g] = __builtin_amdgcn_mfma_f32_16x16x32_bf16(wfr[g], afr[f], acc[f][g], 0, 0, 0);
        __builtin_amdgcn_s_setprio(0);
        BAR();
        // ---- ph1
        #pragma unroll
        for (int f = 0; f < 4; ++f) afr[f] = *(const short8*)(base + aoff[4 + f]);
        if (kt + 1 < 38) STAGE(kt + 1, 1);
        BAR();
        __builtin_amdgcn_s_setprio(1);
        #pragma unroll
        for (int f = 0; f < 4; ++f)
            #pragma unroll
            for (int g = 0; g < 4; ++g)
                acc[4 + f][g] = __builtin_amdgcn_mfma_f32_16x16x32_bf16(wfr[g], afr[f], acc[4 + f][g], 0, 0, 0);
        __builtin_amdgcn_s_setprio(0);
        if (kt + 1 < 38) { VMCNT(4); } else { VMCNT(0); }
        BAR();
        // ---- ph2
        #pragma unroll
        for (int g = 0; g < 4; ++g) wfr[g] = *(const short8*)(base + 16384 + boff[g]);
        #pragma unroll
        for (int f = 0; f < 4; ++f) afr[f] = *(const short8*)(base + 16384 + aoff[f]);
        if (kt + 1 < 38) STAGE(kt + 1, 2);
        BAR();
        __builtin_amdgcn_s_setprio(1);
        #pragma unroll
        for (int f = 0; f < 4; ++f)
            #pragma unroll
            for (int g = 0; g < 4; ++g)
                acc[f][g] = __builtin_amdgcn_mfma_f32_16x16x32_bf16(wfr[g], afr[f], acc[f][g], 0, 0, 0);
        __builtin_amdgcn_s_setprio(0);
        BAR();
        // ---- ph3
        #pragma unroll
        for (int f = 0; f < 4; ++f) afr[f] = *(const short8*)(base + 16384 + aoff[4 + f]);
        if (kt + 1 < 38) STAGE(kt + 1, 3);
        BAR();
        __builtin_amdgcn_s_setprio(1);
        #pragma unroll
        for (int f = 0; f < 4; ++f)
            #pragma unroll
            for (int g = 0; g < 4; ++g)
                acc[4 + f][g] = __builtin_amdgcn_mfma_f32_16x16x32_bf16(wfr[g], afr[f], acc[4 + f][g], 0, 0, 0);
        __builtin_amdgcn_s_setprio(0);
        if (kt + 1 < 38) { VMCNT(4); }
        BAR();
    }

    // epilogue: D rows=oc (kg*4+rg), cols=m (lr); NCHW f32
    #pragma unroll
    for (int fm = 0; fm < 8; ++fm) {
        int mcol = m0 + wm + fm * 16 + lr;
        int n = mcol / 784, pix = mcol % 784;
        float* obase = out + (size_t)n * 200704 + pix;
        #pragma unroll
        for (int fo = 0; fo < 4; ++fo) {
            int ocb = woc + fo * 16 + (kg << 2);
            #pragma unroll
            for (int rg = 0; rg < 4; ++rg) {
                int oc = ocb + rg;
                float v = acc[fm][fo][rg] + b2[oc] + bds[oc];
                obase[(size_t)oc * 784] = fmaxf(v, 0.0f);
            }
        }
    }
}

extern "C" void kernel_launch(void* const* d_in, const int* in_sizes, int n_in,
                              void* d_out, int out_size, void* d_ws, size_t ws_size,
                              hipStream_t stream) {
    const float* x   = (const float*)d_in[0];
    const float* w1  = (const float*)d_in[1];
    const float* b1  = (const float*)d_in[2];
    const float* w2  = (const float*)d_in[3];
    const float* b2  = (const float*)d_in[4];
    const float* wds = (const float*)d_in[5];
    const float* bds = (const float*)d_in[6];
    float* out = (float*)d_out;

    char* ws = (char*)d_ws;
    bf16* xpad   = (bf16*)(ws + OFF_XPAD);
    bf16* actpad = (bf16*)(ws + OFF_ACTPAD);
    bf16* w1t    = (bf16*)(ws + OFF_W1T);
    bf16* w2t    = (bf16*)(ws + OFF_W2T);
    bf16* wdst   = (bf16*)(ws + OFF_WDST);

    halo_zero_kernel<<<1840, 256, 0, stream>>>(xpad, actpad);
    wtrans_kernel<<<2304, 256, 0, stream>>>(w1, w2, wds, w1t, w2t, wdst);
    xpad_kernel<<<64 * 56, 256, 0, stream>>>(x, xpad);
    conv1_kernel<<<196, 512, 0, stream>>>(xpad, w1t, b1, actpad);
    conv2_kernel<<<196, 512, 0, stream>>>(actpad, xpad, w2t, wdst, b2, bds, out);
}

// Round 5
// 334.930 us; speedup vs baseline: 1.0406x; 1.0406x over previous
//
#include <hip/hip_runtime.h>
#include <hip/hip_bf16.h>

typedef short short8 __attribute__((ext_vector_type(8)));
typedef float floatx4 __attribute__((ext_vector_type(4)));
typedef __hip_bfloat16 bf16;

#define GLB(p) ((const __attribute__((address_space(1))) void*)(p))
#define LDSP(p) ((__attribute__((address_space(3))) void*)(p))

__device__ __forceinline__ void gload16(const bf16* g, char* l) {
    __builtin_amdgcn_global_load_lds(GLB(g), LDSP(l), 16, 0, 0);
}

#define VMCNT(n) asm volatile("s_waitcnt vmcnt(" #n ")" ::: "memory")
#define BAR()    __builtin_amdgcn_s_barrier()

// ---- problem sizes ----
// x: (64,128,56,56) f32; out: (64,256,28,28) f32
// xpad:  [64][58][58][128] bf16 (halo=1, conv1 pad baked in)
// actpad:[64][30][30][256] bf16 (halo=1 for conv2 pad)
#define XPAD_BYTES   (64u*58*58*128*2)
#define ACTPAD_BYTES (64u*30*30*256*2)
#define OFF_XPAD   0
#define OFF_ACTPAD (XPAD_BYTES)
#define OFF_W1T    (OFF_ACTPAD + ACTPAD_BYTES)
#define OFF_W2T    (OFF_W1T + 1152u*256*2)
#define OFF_WDST   (OFF_W2T + 2304u*256*2)

// ---------------- weight transforms + halo zero (fused; both trivially parallel)
__global__ void prep_kernel(const float* __restrict__ w1, const float* __restrict__ w2,
                            const float* __restrict__ wds,
                            bf16* __restrict__ w1t, bf16* __restrict__ w2t,
                            bf16* __restrict__ wdst,
                            bf16* __restrict__ xpad, bf16* __restrict__ actpad) {
    int i = blockIdx.x * 256 + threadIdx.x;
    if (i < 256 * 1152) {
        int oc = i / 1152, k = i % 1152, tap = k >> 7, ic = k & 127;
        w1t[i] = __float2bfloat16(w1[(oc * 128 + ic) * 9 + tap]);
    }
    if (i < 256 * 2304) {
        int oc = i / 2304, k = i % 2304, tap = k >> 8, ic = k & 255;
        w2t[i] = __float2bfloat16(w2[(oc * 256 + ic) * 9 + tap]);
    }
    if (i < 256 * 128) {
        wdst[i] = __float2bfloat16(wds[i]); // already [oc][ic]
    }
    // halo zeroing (uint4 = 8 bf16 per thread)
    uint4 z; z.x = z.y = z.z = z.w = 0;
    const int n0 = 64 * 2 * 58 * 16;       // xpad rows h=0,57
    const int n1 = n0 + 64 * 56 * 2 * 16;  // xpad cols w=0,57 (h=1..56)
    const int n2 = n1 + 64 * 2 * 30 * 32;  // actpad rows h=0,29
    const int n3 = n2 + 64 * 28 * 2 * 32;  // actpad cols w=0,29 (h=1..28)
    if (i < n0) {
        int g = i & 15, w = (i >> 4) % 58, q = (i >> 4) / 58;
        int n = q >> 1, h = (q & 1) ? 57 : 0;
        *(uint4*)(xpad + ((size_t)((n * 58 + h) * 58 + w)) * 128 + g * 8) = z;
    } else if (i < n1) {
        int j = i - n0;
        int g = j & 15, q = j >> 4;
        int w = (q & 1) ? 57 : 0, h = (q >> 1) % 56 + 1, n = (q >> 1) / 56;
        *(uint4*)(xpad + ((size_t)((n * 58 + h) * 58 + w)) * 128 + g * 8) = z;
    } else if (i < n2) {
        int j = i - n1;
        int g = j & 31, w = (j >> 5) % 30, q = (j >> 5) / 30;
        int n = q >> 1, h = (q & 1) ? 29 : 0;
        *(uint4*)(actpad + ((size_t)((n * 30 + h) * 30 + w)) * 256 + g * 8) = z;
    } else if (i < n3) {
        int j = i - n2;
        int g = j & 31, q = j >> 5;
        int w = (q & 1) ? 29 : 0, h = (q >> 1) % 28 + 1, n = (q >> 1) / 28;
        *(uint4*)(actpad + ((size_t)((n * 30 + h) * 30 + w)) * 256 + g * 8) = z;
    }
}

// ---------------- x: NCHW f32 -> xpad NHWC bf16 (interior only)
__global__ void xpad_kernel(const float* __restrict__ x, bf16* __restrict__ xpad) {
    int bid = blockIdx.x;
    int n = bid / 56, h = bid % 56;
    __shared__ float tile[128 * 57];
    const float* src = x + ((size_t)n * 128) * 3136 + h * 56;
    for (int e = threadIdx.x; e < 128 * 56; e += 256) {
        int c = e / 56, w = e % 56;
        tile[c * 57 + w] = src[(size_t)c * 3136 + w];
    }
    __syncthreads();
    bf16* dst = xpad + ((size_t)(n * 58 + h + 1) * 58 + 1) * 128;
    for (int e = threadIdx.x; e < 56 * 16; e += 256) {
        int w = e / 16, g = e % 16;
        union { bf16 b[8]; uint4 v; } o;
        #pragma unroll
        for (int j = 0; j < 8; ++j)
            o.b[j] = __float2bfloat16(tile[(g * 8 + j) * 57 + w]);
        *(uint4*)(dst + (size_t)w * 128 + g * 8) = o.v;
    }
}

// LDS slot layout (64KB/slot, 2 slots): chunks c0=Ah0 [0,16K) c2=Ah1 [16K,32K)
//                                        c1=Bh0 [32K,48K) c3=Bh1 [48K,64K)
// chunk = 2 m-halves of 8KB; within half: 128 rows x 64B (4 x 16B units).
// Swizzle (R3-verified, 0 conflicts): LDS[row][u] holds global[row][u ^ ((row>>1)&3)].

// =====================================================================
// conv1: 3x3 s2 p1 + b1 + relu -> actpad. 256m x 256oc, BK=64 (18 kt).
// 4-phase schedule, 2 LDS slots, counted vmcnt(4).
// =====================================================================
__global__ __launch_bounds__(512, 2) void conv1_kernel(
    const bf16* __restrict__ xpad, const bf16* __restrict__ w1t,
    const float* __restrict__ b1, bf16* __restrict__ actpad)
{
    __shared__ __align__(16) char lds[131072];
    const int t = threadIdx.x;
    const int m0 = blockIdx.x * 256;

    const int srow = t >> 2;
    const int su = (t & 3) ^ ((srow >> 1) & 3);   // pre-swizzled source unit
    int xb[2], wb[2];
    #pragma unroll
    for (int r = 0; r < 2; ++r) {
        int m = m0 + r * 128 + srow;
        int n = m / 784, pix = m % 784, oh = pix / 28, ow = pix % 28;
        xb[r] = ((n * 58 + 2 * oh) * 58 + 2 * ow) * 128 + su * 8;
        wb[r] = (r * 128 + srow) * 1152 + su * 8;
    }

    auto STAGE = [&](int kt, int c) {
        constexpr int COFF[4] = {0, 32768, 16384, 49152};
        char* db_ = lds + ((kt & 1) << 16) + COFF[c] + t * 16;
        int h = c >> 1;
        if ((c & 1) == 0) {  // A chunk
            int tap = kt >> 1;
            int kh = (tap * 11) >> 5, kw = tap - kh * 3;
            int toff = (kh * 58 + kw) * 128 + (kt & 1) * 64 + h * 32;
            gload16(xpad + xb[0] + toff, db_);
            gload16(xpad + xb[1] + toff, db_ + 8192);
        } else {             // B chunk
            int koff = kt * 64 + h * 32;
            gload16(w1t + wb[0] + koff, db_);
            gload16(w1t + wb[1] + koff, db_ + 8192);
        }
    };

    const int lane = t & 63, wid = t >> 6;
    const int wm = (wid >> 2) << 7, woc = (wid & 3) << 6;
    const int lr = lane & 15, kg = lane >> 4;
    const int un = (kg ^ ((lr >> 1) & 3)) << 4;   // R3-verified swizzled unit
    int aoff[8], boff[4];
    #pragma unroll
    for (int f = 0; f < 8; ++f) aoff[f] = (wm + f * 16 + lr) * 64 + un;
    #pragma unroll
    for (int g = 0; g < 4; ++g) boff[g] = 32768 + (woc + g * 16 + lr) * 64 + un;

    floatx4 acc[8][4];
    #pragma unroll
    for (int a = 0; a < 8; ++a)
        #pragma unroll
        for (int b = 0; b < 4; ++b) acc[a][b] = (floatx4){0.f, 0.f, 0.f, 0.f};

    STAGE(0, 0); STAGE(0, 1); STAGE(0, 2); STAGE(0, 3);
    VMCNT(4); BAR();

    #pragma unroll 2
    for (int kt = 0; kt < 18; ++kt) {
        const char* base = lds + ((kt & 1) << 16);
        short8 wfr[4], afr[4];
        // ---- ph0: read Bh0 + Ah0[m0..3]; stage c0(kt+1); MFMA m0..3 x h0
        #pragma unroll
        for (int g = 0; g < 4; ++g) wfr[g] = *(const short8*)(base + boff[g]);
        #pragma unroll
        for (int f = 0; f < 4; ++f) afr[f] = *(const short8*)(base + aoff[f]);
        if (kt + 1 < 18) STAGE(kt + 1, 0);
        BAR();
        __builtin_amdgcn_s_setprio(1);
        #pragma unroll
        for (int f = 0; f < 4; ++f)
            #pragma unroll
            for (int g = 0; g < 4; ++g)
                acc[f][g] = __builtin_amdgcn_mfma_f32_16x16x32_bf16(afr[f], wfr[g], acc[f][g], 0, 0, 0);
        __builtin_amdgcn_s_setprio(0);
        BAR();
        // ---- ph1: read Ah0[m4..7]; stage c1(kt+1); MFMA; vmcnt
        #pragma unroll
        for (int f = 0; f < 4; ++f) afr[f] = *(const short8*)(base + aoff[4 + f]);
        if (kt + 1 < 18) STAGE(kt + 1, 1);
        BAR();
        __builtin_amdgcn_s_setprio(1);
        #pragma unroll
        for (int f = 0; f < 4; ++f)
            #pragma unroll
            for (int g = 0; g < 4; ++g)
                acc[4 + f][g] = __builtin_amdgcn_mfma_f32_16x16x32_bf16(afr[f], wfr[g], acc[4 + f][g], 0, 0, 0);
        __builtin_amdgcn_s_setprio(0);
        if (kt + 1 < 18) { VMCNT(4); } else { VMCNT(0); }
        BAR();
        // ---- ph2: read Bh1 + Ah1[m0..3]; stage c2(kt+1); MFMA
        #pragma unroll
        for (int g = 0; g < 4; ++g) wfr[g] = *(const short8*)(base + 16384 + boff[g]);
        #pragma unroll
        for (int f = 0; f < 4; ++f) afr[f] = *(const short8*)(base + 16384 + aoff[f]);
        if (kt + 1 < 18) STAGE(kt + 1, 2);
        BAR();
        __builtin_amdgcn_s_setprio(1);
        #pragma unroll
        for (int f = 0; f < 4; ++f)
            #pragma unroll
            for (int g = 0; g < 4; ++g)
                acc[f][g] = __builtin_amdgcn_mfma_f32_16x16x32_bf16(afr[f], wfr[g], acc[f][g], 0, 0, 0);
        __builtin_amdgcn_s_setprio(0);
        BAR();
        // ---- ph3: read Ah1[m4..7]; stage c3(kt+1); MFMA; vmcnt
        #pragma unroll
        for (int f = 0; f < 4; ++f) afr[f] = *(const short8*)(base + 16384 + aoff[4 + f]);
        if (kt + 1 < 18) STAGE(kt + 1, 3);
        BAR();
        __builtin_amdgcn_s_setprio(1);
        #pragma unroll
        for (int f = 0; f < 4; ++f)
            #pragma unroll
            for (int g = 0; g < 4; ++g)
                acc[4 + f][g] = __builtin_amdgcn_mfma_f32_16x16x32_bf16(afr[f], wfr[g], acc[4 + f][g], 0, 0, 0);
        __builtin_amdgcn_s_setprio(0);
        if (kt + 1 < 18) { VMCNT(4); }
        BAR();
    }

    // epilogue: D rows=m (kg*4+rg), cols=oc (lr)
    #pragma unroll
    for (int fm = 0; fm < 8; ++fm) {
        #pragma unroll
        for (int rg = 0; rg < 4; ++rg) {
            int m = m0 + wm + fm * 16 + (kg << 2) + rg;
            int n = m / 784, pix = m % 784;
            int oh = pix / 28, ow = pix % 28;
            bf16* dst = actpad + ((size_t)(n * 30 + oh + 1) * 30 + (ow + 1)) * 256;
            #pragma unroll
            for (int fo = 0; fo < 4; ++fo) {
                int oc = woc + fo * 16 + lr;
                float v = acc[fm][fo][rg] + b1[oc];
                dst[oc] = __float2bfloat16(fmaxf(v, 0.0f));
            }
        }
    }
}

// =====================================================================
// conv2: 3x3 s1 p1 over actpad + b2 + (1x1 s2 shortcut + bds) + relu -> out.
// 256m x 256oc, K = 2304+128 = 38 kt of 64. Same 4-phase schedule.
// =====================================================================
__global__ __launch_bounds__(512, 2) void conv2_kernel(
    const bf16* __restrict__ actpad, const bf16* __restrict__ xpad,
    const bf16* __restrict__ w2t, const bf16* __restrict__ wdst,
    const float* __restrict__ b2, const float* __restrict__ bds,
    float* __restrict__ out)
{
    __shared__ __align__(16) char lds[131072];
    const int t = threadIdx.x;
    const int m0 = blockIdx.x * 256;

    const int srow = t >> 2;
    const int su = (t & 3) ^ ((srow >> 1) & 3);
    int ab[2], xb[2], wb[2], db2[2];
    #pragma unroll
    for (int r = 0; r < 2; ++r) {
        int m = m0 + r * 128 + srow;
        int n = m / 784, pix = m % 784, oh = pix / 28, ow = pix % 28;
        ab[r]  = ((n * 30 + oh) * 30 + ow) * 256 + su * 8;
        xb[r]  = ((n * 58 + 2 * oh + 1) * 58 + (2 * ow + 1)) * 128 + su * 8;
        wb[r]  = (r * 128 + srow) * 2304 + su * 8;
        db2[r] = (r * 128 + srow) * 128 + su * 8;
    }

    auto STAGE = [&](int kt, int c) {
        constexpr int COFF[4] = {0, 32768, 16384, 49152};
        char* db_ = lds + ((kt & 1) << 16) + COFF[c] + t * 16;
        int h = c >> 1;
        if ((c & 1) == 0) {  // A chunk
            if (kt < 36) {
                int tap = kt >> 2;
                int kh = (tap * 11) >> 5, kw = tap - kh * 3;
                int toff = (kh * 30 + kw) * 256 + (kt & 3) * 64 + h * 32;
                gload16(actpad + ab[0] + toff, db_);
                gload16(actpad + ab[1] + toff, db_ + 8192);
            } else {
                int toff = (kt - 36) * 64 + h * 32;
                gload16(xpad + xb[0] + toff, db_);
                gload16(xpad + xb[1] + toff, db_ + 8192);
            }
        } else {             // B chunk
            if (kt < 36) {
                int koff = kt * 64 + h * 32;
                gload16(w2t + wb[0] + koff, db_);
                gload16(w2t + wb[1] + koff, db_ + 8192);
            } else {
                int koff = (kt - 36) * 64 + h * 32;
                gload16(wdst + db2[0] + koff, db_);
                gload16(wdst + db2[1] + koff, db_ + 8192);
            }
        }
    };

    const int lane = t & 63, wid = t >> 6;
    const int wm = (wid >> 2) << 7, woc = (wid & 3) << 6;
    const int lr = lane & 15, kg = lane >> 4;
    const int un = (kg ^ ((lr >> 1) & 3)) << 4;
    int aoff[8], boff[4];
    #pragma unroll
    for (int f = 0; f < 8; ++f) aoff[f] = (wm + f * 16 + lr) * 64 + un;
    #pragma unroll
    for (int g = 0; g < 4; ++g) boff[g] = 32768 + (woc + g * 16 + lr) * 64 + un;

    floatx4 acc[8][4];
    #pragma unroll
    for (int a = 0; a < 8; ++a)
        #pragma unroll
        for (int b = 0; b < 4; ++b) acc[a][b] = (floatx4){0.f, 0.f, 0.f, 0.f};

    STAGE(0, 0); STAGE(0, 1); STAGE(0, 2); STAGE(0, 3);
    VMCNT(4); BAR();

    #pragma unroll 2
    for (int kt = 0; kt < 38; ++kt) {
        const char* base = lds + ((kt & 1) << 16);
        short8 wfr[4], afr[4];
        // ---- ph0
        #pragma unroll
        for (int g = 0; g < 4; ++g) wfr[g] = *(const short8*)(base + boff[g]);
        #pragma unroll
        for (int f = 0; f < 4; ++f) afr[f] = *(const short8*)(base + aoff[f]);
        if (kt + 1 < 38) STAGE(kt + 1, 0);
        BAR();
        __builtin_amdgcn_s_setprio(1);
        #pragma unroll
        for (int f = 0; f < 4; ++f)
            #pragma unroll
            for (int g = 0; g < 4; ++g)
                acc[f][g] = __builtin_amdgcn_mfma_f32_16x16x32_bf16(wfr[g], afr[f], acc[f][g], 0, 0, 0);
        __builtin_amdgcn_s_setprio(0);
        BAR();
        // ---- ph1
        #pragma unroll
        for (int f = 0; f < 4; ++f) afr[f] = *(const short8*)(base + aoff[4 + f]);
        if (kt + 1 < 38) STAGE(kt + 1, 1);
        BAR();
        __builtin_amdgcn_s_setprio(1);
        #pragma unroll
        for (int f = 0; f < 4; ++f)
            #pragma unroll
            for (int g = 0; g < 4; ++g)
                acc[4 + f][g] = __builtin_amdgcn_mfma_f32_16x16x32_bf16(wfr[g], afr[f], acc[4 + f][g], 0, 0, 0);
        __builtin_amdgcn_s_setprio(0);
        if (kt + 1 < 38) { VMCNT(4); } else { VMCNT(0); }
        BAR();
        // ---- ph2
        #pragma unroll
        for (int g = 0; g < 4; ++g) wfr[g] = *(const short8*)(base + 16384 + boff[g]);
        #pragma unroll
        for (int f = 0; f < 4; ++f) afr[f] = *(const short8*)(base + 16384 + aoff[f]);
        if (kt + 1 < 38) STAGE(kt + 1, 2);
        BAR();
        __builtin_amdgcn_s_setprio(1);
        #pragma unroll
        for (int f = 0; f < 4; ++f)
            #pragma unroll
            for (int g = 0; g < 4; ++g)
                acc[f][g] = __builtin_amdgcn_mfma_f32_16x16x32_bf16(wfr[g], afr[f], acc[f][g], 0, 0, 0);
        __builtin_amdgcn_s_setprio(0);
        BAR();
        // ---- ph3
        #pragma unroll
        for (int f = 0; f < 4; ++f) afr[f] = *(const short8*)(base + 16384 + aoff[4 + f]);
        if (kt + 1 < 38) STAGE(kt + 1, 3);
        BAR();
        __builtin_amdgcn_s_setprio(1);
        #pragma unroll
        for (int f = 0; f < 4; ++f)
            #pragma unroll
            for (int g = 0; g < 4; ++g)
                acc[4 + f][g] = __builtin_amdgcn_mfma_f32_16x16x32_bf16(wfr[g], afr[f], acc[4 + f][g], 0, 0, 0);
        __builtin_amdgcn_s_setprio(0);
        if (kt + 1 < 38) { VMCNT(4); }
        BAR();
    }

    // epilogue: D rows=oc (kg*4+rg), cols=m (lr); NCHW f32
    #pragma unroll
    for (int fm = 0; fm < 8; ++fm) {
        int mcol = m0 + wm + fm * 16 + lr;
        int n = mcol / 784, pix = mcol % 784;
        float* obase = out + (size_t)n * 200704 + pix;
        #pragma unroll
        for (int fo = 0; fo < 4; ++fo) {
            int ocb = woc + fo * 16 + (kg << 2);
            #pragma unroll
            for (int rg = 0; rg < 4; ++rg) {
                int oc = ocb + rg;
                float v = acc[fm][fo][rg] + b2[oc] + bds[oc];
                obase[(size_t)oc * 784] = fmaxf(v, 0.0f);
            }
        }
    }
}

extern "C" void kernel_launch(void* const* d_in, const int* in_sizes, int n_in,
                              void* d_out, int out_size, void* d_ws, size_t ws_size,
                              hipStream_t stream) {
    const float* x   = (const float*)d_in[0];
    const float* w1  = (const float*)d_in[1];
    const float* b1  = (const float*)d_in[2];
    const float* w2  = (const float*)d_in[3];
    const float* b2  = (const float*)d_in[4];
    const float* wds = (const float*)d_in[5];
    const float* bds = (const float*)d_in[6];
    float* out = (float*)d_out;

    char* ws = (char*)d_ws;
    bf16* xpad   = (bf16*)(ws + OFF_XPAD);
    bf16* actpad = (bf16*)(ws + OFF_ACTPAD);
    bf16* w1t    = (bf16*)(ws + OFF_W1T);
    bf16* w2t    = (bf16*)(ws + OFF_W2T);
    bf16* wdst   = (bf16*)(ws + OFF_WDST);

    prep_kernel<<<2304, 256, 0, stream>>>(w1, w2, wds, w1t, w2t, wdst, xpad, actpad);
    xpad_kernel<<<64 * 56, 256, 0, stream>>>(x, xpad);
    conv1_kernel<<<196, 512, 0, stream>>>(xpad, w1t, b1, actpad);
    conv2_kernel<<<196, 512, 0, stream>>>(actpad, xpad, w2t, wdst, b2, bds, out);
}

// Round 6
// 319.944 us; speedup vs baseline: 1.0894x; 1.0468x over previous
//
#include <hip/hip_runtime.h>
#include <hip/hip_bf16.h>

typedef short short8 __attribute__((ext_vector_type(8)));
typedef float floatx4 __attribute__((ext_vector_type(4)));
typedef __hip_bfloat16 bf16;

#define GLB(p) ((const __attribute__((address_space(1))) void*)(p))
#define LDSP(p) ((__attribute__((address_space(3))) void*)(p))

__device__ __forceinline__ void gload16(const bf16* g, char* l) {
    __builtin_amdgcn_global_load_lds(GLB(g), LDSP(l), 16, 0, 0);
}

#define VMCNT(n) asm volatile("s_waitcnt vmcnt(" #n ")" ::: "memory")
#define BAR()    __builtin_amdgcn_s_barrier()

// ---- problem sizes ----
// x: (64,128,56,56) f32; out: (64,256,28,28) f32
// xpad:  [64][58][58][128] bf16 (halo=1, conv1 pad baked in)
// actpad:[64][30][30][256] bf16 (halo=1 for conv2 pad)
#define XPAD_BYTES   (64u*58*58*128*2)
#define ACTPAD_BYTES (64u*30*30*256*2)
#define OFF_XPAD   0
#define OFF_ACTPAD (XPAD_BYTES)
#define OFF_W1T    (OFF_ACTPAD + ACTPAD_BYTES)
#define OFF_W2T    (OFF_W1T + 1152u*256*2)
#define OFF_WDST   (OFF_W2T + 2304u*256*2)

// ---------------- weight transforms + halo zero (fused)
__global__ void prep_kernel(const float* __restrict__ w1, const float* __restrict__ w2,
                            const float* __restrict__ wds,
                            bf16* __restrict__ w1t, bf16* __restrict__ w2t,
                            bf16* __restrict__ wdst,
                            bf16* __restrict__ xpad, bf16* __restrict__ actpad) {
    int i = blockIdx.x * 256 + threadIdx.x;
    if (i < 256 * 1152) {
        int oc = i / 1152, k = i % 1152, tap = k >> 7, ic = k & 127;
        w1t[i] = __float2bfloat16(w1[(oc * 128 + ic) * 9 + tap]);
    }
    if (i < 256 * 2304) {
        int oc = i / 2304, k = i % 2304, tap = k >> 8, ic = k & 255;
        w2t[i] = __float2bfloat16(w2[(oc * 256 + ic) * 9 + tap]);
    }
    if (i < 256 * 128) {
        wdst[i] = __float2bfloat16(wds[i]); // already [oc][ic]
    }
    uint4 z; z.x = z.y = z.z = z.w = 0;
    const int n0 = 64 * 2 * 58 * 16;
    const int n1 = n0 + 64 * 56 * 2 * 16;
    const int n2 = n1 + 64 * 2 * 30 * 32;
    const int n3 = n2 + 64 * 28 * 2 * 32;
    if (i < n0) {
        int g = i & 15, w = (i >> 4) % 58, q = (i >> 4) / 58;
        int n = q >> 1, h = (q & 1) ? 57 : 0;
        *(uint4*)(xpad + ((size_t)((n * 58 + h) * 58 + w)) * 128 + g * 8) = z;
    } else if (i < n1) {
        int j = i - n0;
        int g = j & 15, q = j >> 4;
        int w = (q & 1) ? 57 : 0, h = (q >> 1) % 56 + 1, n = (q >> 1) / 56;
        *(uint4*)(xpad + ((size_t)((n * 58 + h) * 58 + w)) * 128 + g * 8) = z;
    } else if (i < n2) {
        int j = i - n1;
        int g = j & 31, w = (j >> 5) % 30, q = (j >> 5) / 30;
        int n = q >> 1, h = (q & 1) ? 29 : 0;
        *(uint4*)(actpad + ((size_t)((n * 30 + h) * 30 + w)) * 256 + g * 8) = z;
    } else if (i < n3) {
        int j = i - n2;
        int g = j & 31, q = j >> 5;
        int w = (q & 1) ? 29 : 0, h = (q >> 1) % 28 + 1, n = (q >> 1) / 28;
        *(uint4*)(actpad + ((size_t)((n * 30 + h) * 30 + w)) * 256 + g * 8) = z;
    }
}

// ---------------- x: NCHW f32 -> xpad NHWC bf16 (interior only)
__global__ void xpad_kernel(const float* __restrict__ x, bf16* __restrict__ xpad) {
    int bid = blockIdx.x;
    int n = bid / 56, h = bid % 56;
    __shared__ float tile[128 * 57];
    const float* src = x + ((size_t)n * 128) * 3136 + h * 56;
    for (int e = threadIdx.x; e < 128 * 56; e += 256) {
        int c = e / 56, w = e % 56;
        tile[c * 57 + w] = src[(size_t)c * 3136 + w];
    }
    __syncthreads();
    bf16* dst = xpad + ((size_t)(n * 58 + h + 1) * 58 + 1) * 128;
    for (int e = threadIdx.x; e < 56 * 16; e += 256) {
        int w = e / 16, g = e % 16;
        union { bf16 b[8]; uint4 v; } o;
        #pragma unroll
        for (int j = 0; j < 8; ++j)
            o.b[j] = __float2bfloat16(tile[(g * 8 + j) * 57 + w]);
        *(uint4*)(dst + (size_t)w * 128 + g * 8) = o.v;
    }
}

// LDS slot layout (64KB/slot, 2 slots): c0=Ah0 [0,16K) c2=Ah1 [16K,32K)
//                                        c1=Bh0 [32K,48K) c3=Bh1 [48K,64K)
// A chunk = 256 rows x 32 k-cols (64B/row); rows 0-127 at +0, 128-255 at +8192.
// Swizzle (R3-verified 0-conflict): LDS[row][u16] = global[row][u16 ^ ((row>>1)&3)].

#define MFMA16_AB(ACCBASE)                                                            \
    _Pragma("unroll")                                                                 \
    for (int f = 0; f < 4; ++f)                                                       \
        _Pragma("unroll")                                                             \
        for (int g = 0; g < 4; ++g)                                                   \
            acc[(ACCBASE) + f][g] =                                                   \
                __builtin_amdgcn_mfma_f32_16x16x32_bf16(afr[f], wfr[g], acc[(ACCBASE) + f][g], 0, 0, 0);

#define MFMA16_BA(ACCBASE)                                                            \
    _Pragma("unroll")                                                                 \
    for (int f = 0; f < 4; ++f)                                                       \
        _Pragma("unroll")                                                             \
        for (int g = 0; g < 4; ++g)                                                   \
            acc[(ACCBASE) + f][g] =                                                   \
                __builtin_amdgcn_mfma_f32_16x16x32_bf16(wfr[g], afr[f], acc[(ACCBASE) + f][g], 0, 0, 0);

// =====================================================================
// conv1: 3x3 s2 p1 + b1 + relu -> actpad. 256m x 256oc, 18 kt of 64.
// Minimal-sync loop: 1 barrier + 2x vmcnt(4) per kt64.
// =====================================================================
__global__ __launch_bounds__(512, 2) void conv1_kernel(
    const bf16* __restrict__ xpad, const bf16* __restrict__ w1t,
    const float* __restrict__ b1, bf16* __restrict__ actpad)
{
    __shared__ __align__(16) char lds[131072];
    const int t = threadIdx.x;
    const int m0 = blockIdx.x * 256;

    const int srow = t >> 2;
    const int su = (t & 3) ^ ((srow >> 1) & 3);
    int xb[2], wb[2];
    #pragma unroll
    for (int r = 0; r < 2; ++r) {
        int m = m0 + r * 128 + srow;
        int n = m / 784, pix = m % 784, oh = pix / 28, ow = pix % 28;
        xb[r] = ((n * 58 + 2 * oh) * 58 + 2 * ow) * 128 + su * 8;
        wb[r] = (r * 128 + srow) * 1152 + su * 8;
    }

    auto STAGE = [&](int kt, int c) {
        constexpr int COFF[4] = {0, 32768, 16384, 49152};
        char* db_ = lds + ((kt & 1) << 16) + COFF[c] + t * 16;
        int h = c >> 1;
        if ((c & 1) == 0) {
            int tap = kt >> 1;
            int kh = (tap * 11) >> 5, kw = tap - kh * 3;
            int toff = (kh * 58 + kw) * 128 + (kt & 1) * 64 + h * 32;
            gload16(xpad + xb[0] + toff, db_);
            gload16(xpad + xb[1] + toff, db_ + 8192);
        } else {
            int koff = kt * 64 + h * 32;
            gload16(w1t + wb[0] + koff, db_);
            gload16(w1t + wb[1] + koff, db_ + 8192);
        }
    };

    const int lane = t & 63, wid = t >> 6;
    const int wm = (wid >> 2) << 7, woc = (wid & 3) << 6;
    const int lr = lane & 15, kg = lane >> 4;
    const int un = (kg ^ ((lr >> 1) & 3)) << 4;
    int aoff[8], boff[4];
    #pragma unroll
    for (int f = 0; f < 8; ++f) aoff[f] = (wm + f * 16 + lr) * 64 + un;
    #pragma unroll
    for (int g = 0; g < 4; ++g) boff[g] = 32768 + (woc + g * 16 + lr) * 64 + un;

    floatx4 acc[8][4];
    #pragma unroll
    for (int a = 0; a < 8; ++a)
        #pragma unroll
        for (int b = 0; b < 4; ++b) acc[a][b] = (floatx4){0.f, 0.f, 0.f, 0.f};

    STAGE(0, 0); STAGE(0, 1); STAGE(0, 2); STAGE(0, 3);
    VMCNT(4); BAR();

    #pragma unroll 2
    for (int kt = 0; kt < 18; ++kt) {
        const char* base = lds + ((kt & 1) << 16);
        const bool pf = (kt + 1 < 18);
        short8 wfr[4], afr[4];
        // ---- k-half 0 ----
        #pragma unroll
        for (int g = 0; g < 4; ++g) wfr[g] = *(const short8*)(base + boff[g]);
        #pragma unroll
        for (int f = 0; f < 4; ++f) afr[f] = *(const short8*)(base + aoff[f]);
        if (pf) { STAGE(kt + 1, 0); STAGE(kt + 1, 1); }
        __builtin_amdgcn_s_setprio(1);
        MFMA16_AB(0)
        __builtin_amdgcn_s_setprio(0);
        #pragma unroll
        for (int f = 0; f < 4; ++f) afr[f] = *(const short8*)(base + aoff[4 + f]);
        __builtin_amdgcn_s_setprio(1);
        MFMA16_AB(4)
        __builtin_amdgcn_s_setprio(0);
        if (pf) { VMCNT(4); } else { VMCNT(0); }
        // ---- k-half 1 ----
        #pragma unroll
        for (int g = 0; g < 4; ++g) wfr[g] = *(const short8*)(base + 16384 + boff[g]);
        #pragma unroll
        for (int f = 0; f < 4; ++f) afr[f] = *(const short8*)(base + 16384 + aoff[f]);
        if (pf) { STAGE(kt + 1, 2); STAGE(kt + 1, 3); }
        __builtin_amdgcn_s_setprio(1);
        MFMA16_AB(0)
        __builtin_amdgcn_s_setprio(0);
        #pragma unroll
        for (int f = 0; f < 4; ++f) afr[f] = *(const short8*)(base + 16384 + aoff[4 + f]);
        __builtin_amdgcn_s_setprio(1);
        MFMA16_AB(4)
        __builtin_amdgcn_s_setprio(0);
        if (pf) { VMCNT(4); }
        BAR();
    }

    // epilogue: D rows=m (kg*4+rg), cols=oc (lr)
    #pragma unroll
    for (int fm = 0; fm < 8; ++fm) {
        #pragma unroll
        for (int rg = 0; rg < 4; ++rg) {
            int m = m0 + wm + fm * 16 + (kg << 2) + rg;
            int n = m / 784, pix = m % 784;
            int oh = pix / 28, ow = pix % 28;
            bf16* dst = actpad + ((size_t)(n * 30 + oh + 1) * 30 + (ow + 1)) * 256;
            #pragma unroll
            for (int fo = 0; fo < 4; ++fo) {
                int oc = woc + fo * 16 + lr;
                float v = acc[fm][fo][rg] + b1[oc];
                dst[oc] = __float2bfloat16(fmaxf(v, 0.0f));
            }
        }
    }
}

// =====================================================================
// conv2: 3x3 s1 p1 over actpad + b2 + (1x1 s2 shortcut + bds) + relu -> out.
// 256m x 256oc, K = 2304+128 = 38 kt of 64. Same minimal-sync loop.
// =====================================================================
__global__ __launch_bounds__(512, 2) void conv2_kernel(
    const bf16* __restrict__ actpad, const bf16* __restrict__ xpad,
    const bf16* __restrict__ w2t, const bf16* __restrict__ wdst,
    const float* __restrict__ b2, const float* __restrict__ bds,
    float* __restrict__ out)
{
    __shared__ __align__(16) char lds[131072];
    const int t = threadIdx.x;
    const int m0 = blockIdx.x * 256;

    const int srow = t >> 2;
    const int su = (t & 3) ^ ((srow >> 1) & 3);
    int ab[2], xb[2], wb[2], db2[2];
    #pragma unroll
    for (int r = 0; r < 2; ++r) {
        int m = m0 + r * 128 + srow;
        int n = m / 784, pix = m % 784, oh = pix / 28, ow = pix % 28;
        ab[r]  = ((n * 30 + oh) * 30 + ow) * 256 + su * 8;
        xb[r]  = ((n * 58 + 2 * oh + 1) * 58 + (2 * ow + 1)) * 128 + su * 8;
        wb[r]  = (r * 128 + srow) * 2304 + su * 8;
        db2[r] = (r * 128 + srow) * 128 + su * 8;
    }

    auto STAGE = [&](int kt, int c) {
        constexpr int COFF[4] = {0, 32768, 16384, 49152};
        char* db_ = lds + ((kt & 1) << 16) + COFF[c] + t * 16;
        int h = c >> 1;
        if ((c & 1) == 0) {
            if (kt < 36) {
                int tap = kt >> 2;
                int kh = (tap * 11) >> 5, kw = tap - kh * 3;
                int toff = (kh * 30 + kw) * 256 + (kt & 3) * 64 + h * 32;
                gload16(actpad + ab[0] + toff, db_);
                gload16(actpad + ab[1] + toff, db_ + 8192);
            } else {
                int toff = (kt - 36) * 64 + h * 32;
                gload16(xpad + xb[0] + toff, db_);
                gload16(xpad + xb[1] + toff, db_ + 8192);
            }
        } else {
            if (kt < 36) {
                int koff = kt * 64 + h * 32;
                gload16(w2t + wb[0] + koff, db_);
                gload16(w2t + wb[1] + koff, db_ + 8192);
            } else {
                int koff = (kt - 36) * 64 + h * 32;
                gload16(wdst + db2[0] + koff, db_);
                gload16(wdst + db2[1] + koff, db_ + 8192);
            }
        }
    };

    const int lane = t & 63, wid = t >> 6;
    const int wm = (wid >> 2) << 7, woc = (wid & 3) << 6;
    const int lr = lane & 15, kg = lane >> 4;
    const int un = (kg ^ ((lr >> 1) & 3)) << 4;
    int aoff[8], boff[4];
    #pragma unroll
    for (int f = 0; f < 8; ++f) aoff[f] = (wm + f * 16 + lr) * 64 + un;
    #pragma unroll
    for (int g = 0; g < 4; ++g) boff[g] = 32768 + (woc + g * 16 + lr) * 64 + un;

    floatx4 acc[8][4];
    #pragma unroll
    for (int a = 0; a < 8; ++a)
        #pragma unroll
        for (int b = 0; b < 4; ++b) acc[a][b] = (floatx4){0.f, 0.f, 0.f, 0.f};

    STAGE(0, 0); STAGE(0, 1); STAGE(0, 2); STAGE(0, 3);
    VMCNT(4); BAR();

    #pragma unroll 2
    for (int kt = 0; kt < 38; ++kt) {
        const char* base = lds + ((kt & 1) << 16);
        const bool pf = (kt + 1 < 38);
        short8 wfr[4], afr[4];
        // ---- k-half 0 ----
        #pragma unroll
        for (int g = 0; g < 4; ++g) wfr[g] = *(const short8*)(base + boff[g]);
        #pragma unroll
        for (int f = 0; f < 4; ++f) afr[f] = *(const short8*)(base + aoff[f]);
        if (pf) { STAGE(kt + 1, 0); STAGE(kt + 1, 1); }
        __builtin_amdgcn_s_setprio(1);
        MFMA16_BA(0)
        __builtin_amdgcn_s_setprio(0);
        #pragma unroll
        for (int f = 0; f < 4; ++f) afr[f] = *(const short8*)(base + aoff[4 + f]);
        __builtin_amdgcn_s_setprio(1);
        MFMA16_BA(4)
        __builtin_amdgcn_s_setprio(0);
        if (pf) { VMCNT(4); } else { VMCNT(0); }
        // ---- k-half 1 ----
        #pragma unroll
        for (int g = 0; g < 4; ++g) wfr[g] = *(const short8*)(base + 16384 + boff[g]);
        #pragma unroll
        for (int f = 0; f < 4; ++f) afr[f] = *(const short8*)(base + 16384 + aoff[f]);
        if (pf) { STAGE(kt + 1, 2); STAGE(kt + 1, 3); }
        __builtin_amdgcn_s_setprio(1);
        MFMA16_BA(0)
        __builtin_amdgcn_s_setprio(0);
        #pragma unroll
        for (int f = 0; f < 4; ++f) afr[f] = *(const short8*)(base + 16384 + aoff[4 + f]);
        __builtin_amdgcn_s_setprio(1);
        MFMA16_BA(4)
        __builtin_amdgcn_s_setprio(0);
        if (pf) { VMCNT(4); }
        BAR();
    }

    // epilogue: D rows=oc (kg*4+rg), cols=m (lr); NCHW f32
    #pragma unroll
    for (int fm = 0; fm < 8; ++fm) {
        int mcol = m0 + wm + fm * 16 + lr;
        int n = mcol / 784, pix = mcol % 784;
        float* obase = out + (size_t)n * 200704 + pix;
        #pragma unroll
        for (int fo = 0; fo < 4; ++fo) {
            int ocb = woc + fo * 16 + (kg << 2);
            #pragma unroll
            for (int rg = 0; rg < 4; ++rg) {
                int oc = ocb + rg;
                float v = acc[fm][fo][rg] + b2[oc] + bds[oc];
                obase[(size_t)oc * 784] = fmaxf(v, 0.0f);
            }
        }
    }
}

extern "C" void kernel_launch(void* const* d_in, const int* in_sizes, int n_in,
                              void* d_out, int out_size, void* d_ws, size_t ws_size,
                              hipStream_t stream) {
    const float* x   = (const float*)d_in[0];
    const float* w1  = (const float*)d_in[1];
    const float* b1  = (const float*)d_in[2];
    const float* w2  = (const float*)d_in[3];
    const float* b2  = (const float*)d_in[4];
    const float* wds = (const float*)d_in[5];
    const float* bds = (const float*)d_in[6];
    float* out = (float*)d_out;

    char* ws = (char*)d_ws;
    bf16* xpad   = (bf16*)(ws + OFF_XPAD);
    bf16* actpad = (bf16*)(ws + OFF_ACTPAD);
    bf16* w1t    = (bf16*)(ws + OFF_W1T);
    bf16* w2t    = (bf16*)(ws + OFF_W2T);
    bf16* wdst   = (bf16*)(ws + OFF_WDST);

    prep_kernel<<<2304, 256, 0, stream>>>(w1, w2, wds, w1t, w2t, wdst, xpad, actpad);
    xpad_kernel<<<64 * 56, 256, 0, stream>>>(x, xpad);
    conv1_kernel<<<196, 512, 0, stream>>>(xpad, w1t, b1, actpad);
    conv2_kernel<<<196, 512, 0, stream>>>(actpad, xpad, w2t, wdst, b2, bds, out);
}